// Round 19
// baseline (329.639 us; speedup 1.0000x reference)
//
#include <hip/hip_runtime.h>

#define NN 4096
#define FF 128
#define EE 64

typedef unsigned short u16;
typedef unsigned long long u64;
typedef float vf4 __attribute__((ext_vector_type(4)));

__device__ __forceinline__ float lrelu(float x) { return x > 0.f ? x : 0.2f * x; }

// K1: 16 nodes per block, 256 blocks. vv (= W_d @ a_d, 6 combos) computed
// per-block wave-cooperatively with COALESCED W loads (R17's bug: aa[256..383]
// unfilled by `if(tid<384)` with 256 threads — fixed with a strided loop).
// u = t@W.T via LDS-staged weight; out rows 0..63 as FULL 64-B LINES; s1/p;
// blocks 0..15 zero the CSC counters. Replaces the separate k_prep dispatch.
__global__ __launch_bounds__(256)
void k_feat(const float* __restrict__ t, const float* __restrict__ weight,
            const float* __restrict__ Wf, const float* __restrict__ af1, const float* __restrict__ af2,
            const float* __restrict__ Wb, const float* __restrict__ ab1, const float* __restrict__ ab2,
            const float* __restrict__ Wg, const float* __restrict__ ag1, const float* __restrict__ ag2,
            float* __restrict__ u, float* __restrict__ s1, float* __restrict__ p,
            float* __restrict__ out, int* __restrict__ ccnt)
{
    __shared__ float ww[64 * 129];   // weight[e][q] at e*129+q  (129: bank-spread)
    __shared__ float tt[16 * 130];   // t[node][q] at node*130+q
    __shared__ float vv[6 * FF];
    __shared__ float aa[6 * 64];     // the six a-vectors
    __shared__ float uacc[64 * 17];  // u[e][node] staging for transposed out write
    const float* Ws[3]  = {Wf, Wb, Wg};
    const float* a1s[3] = {af1, ab1, ag1};
    const float* a2s[3] = {af2, ab2, ag2};
    int b = blockIdx.x, tid = threadIdx.x, wid = tid >> 6, lane = tid & 63;
    int n0 = b * 16;
    if (b < 16) ccnt[b * 256 + tid] = 0;
    for (int i = tid; i < 384; i += 256) {          // FIXED: covers all 384 slots
        int vi = i >> 6, e = i & 63, dd = vi >> 1;
        const float* a = (vi & 1) ? a2s[dd] : a1s[dd];
        aa[i] = a[e];
    }
    const float4* w4 = reinterpret_cast<const float4*>(weight);
    for (int i = tid; i < 2048; i += 256) {
        float4 v = w4[i];
        int fi = i * 4, e = fi >> 7, q = fi & 127;
        float* dst = &ww[e * 129 + q];
        dst[0] = v.x; dst[1] = v.y; dst[2] = v.z; dst[3] = v.w;
    }
    const float4* t4 = reinterpret_cast<const float4*>(t + (size_t)n0 * FF);
    for (int i = tid; i < 512; i += 256) {
        float4 v = t4[i];
        int fi = i * 4, nd = fi >> 7, q = fi & 127;
        float* dst = &tt[nd * 130 + q];
        dst[0] = v.x; dst[1] = v.y; dst[2] = v.z; dst[3] = v.w;
    }
    __syncthreads();
    // vv: one dot-64 per wave-iteration, coalesced W row load + shfl reduce
    for (int item = wid; item < 768; item += 4) {
        int vi = item >> 7, f = item & 127, dd = vi >> 1;
        float prod = Ws[dd][(size_t)f * EE + lane] * aa[vi * 64 + lane];
        for (int off = 32; off; off >>= 1) prod += __shfl_xor(prod, off);
        if (lane == 0) vv[vi * FF + f] = prod;
    }
    __syncthreads();
    for (int k = 0; k < 4; ++k) {
        int nd = wid * 4 + k;
        const float* trow = &tt[nd * 130];
        const float* wrow = &ww[lane * 129];
        float acc = 0.f;
        #pragma unroll 16
        for (int q = 0; q < 128; ++q) acc += wrow[q] * trow[q];
        u[(size_t)(n0 + nd) * EE + lane] = acc;
        uacc[lane * 17 + nd] = acc;
        float t0 = trow[lane], t1 = trow[64 + lane];
        for (int vi = 0; vi < 6; ++vi) {
            float x = t0 * vv[vi * FF + lane] + t1 * vv[vi * FF + 64 + lane];
            for (int off = 32; off; off >>= 1) x += __shfl_xor(x, off);
            if (lane == 0) {
                int dd = vi >> 1;
                if (vi & 1) p[dd * NN + n0 + nd] = x; else s1[dd * NN + n0 + nd] = x;
            }
        }
    }
    __syncthreads();
    int e = tid >> 2, io = (tid & 3) * 4;
    float* orow = out + (size_t)e * NN + n0 + io;
    orow[0] = uacc[e * 17 + io];
    orow[1] = uacc[e * 17 + io + 1];
    orow[2] = uacc[e * 17 + io + 2];
    orow[3] = uacc[e * 17 + io + 3];
}

// K2: streaming scan with NON-TEMPORAL adjacency loads (R16/R18-proven:
// 77 -> 42 us). ONE WAVE = ONE ROW.
__global__ __launch_bounds__(256, 8)
void k_scan(const float* __restrict__ Af, const float* __restrict__ Ab, const float* __restrict__ Ag,
            const float* __restrict__ p,
            u16* __restrict__ csr, int* __restrict__ cnt, float* __restrict__ s2,
            u16* __restrict__ csc, int* __restrict__ ccnt, int stride)
{
    int wid = threadIdx.x >> 6, lane = threadIdx.x & 63;
    int gr = blockIdx.x * 4 + wid;             // 0 .. 3*NN-1
    int d = gr >> 12, r = gr & (NN - 1);
    const float* A = d == 0 ? Af : (d == 1 ? Ab : Ag);
    const vf4* row4 = reinterpret_cast<const vf4*>(A + (size_t)r * NN);
    const float* pd = p + d * NN;

    u64 mask = 0ull;
    #pragma unroll
    for (int j = 0; j < 16; ++j) {
        vf4 L = __builtin_nontemporal_load(row4 + j * 64 + lane);
        unsigned mm = (L.x != 0.f ? 1u : 0u) | (L.y != 0.f ? 2u : 0u) |
                      (L.z != 0.f ? 4u : 0u) | (L.w != 0.f ? 8u : 0u);
        mask |= ((u64)mm) << (j * 4);
    }

    int lc = __popcll(mask);
    int sc = lc;
    for (int off = 1; off < 64; off <<= 1) {
        int o = __shfl_up(sc, off);
        if (lane >= off) sc += o;
    }
    int total = __shfl(sc, 63);
    int pos = sc - lc;
    u16* crow = csr + (size_t)gr * stride;
    float q = 0.f;
    u64 m = mask;
    while (m) {
        int b = __ffsll(m) - 1;
        m &= m - 1;
        int col = ((b >> 2) << 8) + (lane << 2) + (b & 3);
        if (pos < stride) crow[pos] = (u16)col;
        pos++;
        q += pd[col];
        if (d == 1) {
            int cp = atomicAdd(&ccnt[col], 1);
            if (cp < stride) csc[(size_t)col * stride + cp] = (u16)r;
        }
    }
    for (int off = 32; off; off >>= 1) q += __shfl_xor(q, off);
    if (lane == 0) {
        cnt[gr] = total;
        s2[gr] = q / fmaxf((float)total, 1.f);
    }
}

// K3: zpack[j] = (s1b[j], 1/Zb[j]) — packed so k_out's bwd phase needs ONE
// 8-B gather per entry instead of two dependent 4-B gathers.
__global__ void k_zb(const float* __restrict__ s1, const float* __restrict__ s2,
                     const u16* __restrict__ csr, const int* __restrict__ cnt, int stride,
                     float2* __restrict__ zpack)
{
    int tid = threadIdx.x, wave = tid >> 6, lane = tid & 63;
    int j = blockIdx.x * 4 + wave;
    int gr = NN + j;
    int nnz = min(cnt[gr], stride);
    const u16* crow = csr + (size_t)gr * stride;
    float s1j = s1[gr];
    const float* s2b = s2 + NN;
    float z = 0.f;
    if (lane < nnz)      z += __expf(lrelu(s1j + s2b[crow[lane]]));
    if (lane + 64 < nnz) z += __expf(lrelu(s1j + s2b[crow[lane + 64]]));
    for (int off = 32; off; off >>= 1) z += __shfl_xor(z, off);
    if (lane == 0) zpack[j] = make_float2(s1j, z > 0.f ? 1.f / z : 0.f);
}

// K4: unified consumer, 1024 threads = 16 waves, 16 rows/block, ONE WAVE PER
// ROW in a single round (serial gather depth 84 -> ~21 dependent L2 steps).
// Full 64-B-line transposed writes (one store/thread).
//  d==0: fwd (CSR) -> rows 64..127 ; d==1: bwd (CSC) -> 128..191 ; d==2: geo -> 192..255
__global__ __launch_bounds__(1024)
void k_out(const float* __restrict__ u,
           const float* __restrict__ s1, const float* __restrict__ s2,
           const float2* __restrict__ zpack,
           const u16* __restrict__ csr, const int* __restrict__ cnt,
           const u16* __restrict__ csc, const int* __restrict__ ccnt, int stride,
           float* __restrict__ out)
{
    __shared__ float oacc[16 * 66];
    int gr0 = blockIdx.x * 16;
    int d = gr0 >> 12, i0 = gr0 & (NN - 1);
    int tid = threadIdx.x, wid = tid >> 6, lane = tid & 63;
    int lr = wid;                   // one wave per row
    int i = i0 + lr;
    int gr = gr0 + lr;
    int nnz;
    int c0v = 0, c1v = 0;
    float w0v = 0.f, w1v = 0.f;
    if (d == 1) {
        nnz = min(ccnt[i], stride);
        const u16* cc = csc + (size_t)i * stride;
        float s2i = s2[NN + i];
        if (lane < nnz)      { int j = cc[lane];      float2 z = zpack[j]; c0v = j; w0v = __expf(lrelu(z.x + s2i)) * z.y; }
        if (lane + 64 < nnz) { int j = cc[lane + 64]; float2 z = zpack[j]; c1v = j; w1v = __expf(lrelu(z.x + s2i)) * z.y; }
    } else {
        nnz = min(cnt[gr], stride);
        const u16* crow = csr + (size_t)gr * stride;
        float s1i = s1[gr];
        const float* s2d = s2 + d * NN;
        float z = 0.f;
        if (lane < nnz)      { int c = crow[lane];      c0v = c; w0v = __expf(lrelu(s1i + s2d[c])); z += w0v; }
        if (lane + 64 < nnz) { int c = crow[lane + 64]; c1v = c; w1v = __expf(lrelu(s1i + s2d[c])); z += w1v; }
        for (int off = 32; off; off >>= 1) z += __shfl_xor(z, off);
        float invz = z > 0.f ? 1.f / z : 0.f;
        w0v *= invz; w1v *= invz;
    }
    float a0 = 0.f, a1 = 0.f;
    int n0 = nnz < 64 ? nnz : 64;
    int kk = 0;
    for (; kk + 1 < n0; kk += 2) {
        int ca = __shfl(c0v, kk), cb = __shfl(c0v, kk + 1);
        float wa = __shfl(w0v, kk), wb = __shfl(w0v, kk + 1);
        a0 += wa * u[(size_t)ca * EE + lane];
        a1 += wb * u[(size_t)cb * EE + lane];
    }
    if (kk < n0)
        a0 += __shfl(w0v, kk) * u[(size_t)__shfl(c0v, kk) * EE + lane];
    int n1 = nnz - 64;
    kk = 0;
    for (; kk + 1 < n1; kk += 2) {
        int ca = __shfl(c1v, kk), cb = __shfl(c1v, kk + 1);
        float wa = __shfl(w1v, kk), wb = __shfl(w1v, kk + 1);
        a0 += wa * u[(size_t)ca * EE + lane];
        a1 += wb * u[(size_t)cb * EE + lane];
    }
    if (kk < n1)
        a0 += __shfl(w1v, kk) * u[(size_t)__shfl(c1v, kk) * EE + lane];
    oacc[lr * 66 + lane] = a0 + a1;
    __syncthreads();
    int e = tid >> 4, io = tid & 15;
    int base = 64 + (d << 6);
    out[(size_t)(base + e) * NN + i0 + io] = oacc[io * 66 + e];
}

extern "C" void kernel_launch(void* const* d_in, const int* in_sizes, int n_in,
                              void* d_out, int out_size, void* d_ws, size_t ws_size,
                              hipStream_t stream)
{
    const float* t   = (const float*)d_in[0];
    const float* Ag  = (const float*)d_in[1];
    const float* Af  = (const float*)d_in[2];
    const float* Ab  = (const float*)d_in[3];
    const float* W   = (const float*)d_in[4];
    const float* Wf  = (const float*)d_in[5];
    const float* af1 = (const float*)d_in[6];
    const float* af2 = (const float*)d_in[7];
    const float* Wb  = (const float*)d_in[8];
    const float* ab1 = (const float*)d_in[9];
    const float* ab2 = (const float*)d_in[10];
    const float* Wg  = (const float*)d_in[11];
    const float* ag1 = (const float*)d_in[12];
    const float* ag2 = (const float*)d_in[13];
    float* out = (float*)d_out;

    float* ws = (float*)d_ws;
    float*  s1    = ws;                             // 3N
    float*  p     = s1 + 3 * NN;                    // 3N
    float*  s2    = p + 3 * NN;                     // 3N
    float2* zpack = (float2*)(s2 + 3 * NN);         // N float2 = 2N floats
    float*  u     = (float*)(zpack + NN);           // N*E
    int*    cnt   = (int*)(u + (size_t)NN * EE);    // 3N
    int*    ccnt  = cnt + 3 * NN;                   // N
    u16*    csr   = (u16*)(ccnt + NN);              // 3N*stride
    // csc follows csr: N*stride

    size_t base_bytes = ((char*)csr) - ((char*)d_ws);
    int stride = 128;
    if (base_bytes + (size_t)4 * NN * 128 * 2 > ws_size) stride = 96;
    if (base_bytes + (size_t)4 * NN * 96 * 2 > ws_size)  stride = 64;
    u16* csc = csr + (size_t)3 * NN * stride;

    k_feat<<<NN / 16, 256, 0, stream>>>(t, W, Wf, af1, af2, Wb, ab1, ab2, Wg, ag1, ag2,
                                        u, s1, p, out, ccnt);
    k_scan<<<3 * NN / 4, 256, 0, stream>>>(Af, Ab, Ag, p, csr, cnt, s2, csc, ccnt, stride);
    k_zb<<<NN / 4, 256, 0, stream>>>(s1, s2, csr, cnt, stride, zpack);
    k_out<<<3 * NN / 16, 1024, 0, stream>>>(u, s1, s2, zpack, csr, cnt, csc, ccnt, stride, out);
}

// Round 20
// 254.795 us; speedup vs baseline: 1.2937x; 1.2937x over previous
//
#include <hip/hip_runtime.h>

#define NN 4096
#define FF 128
#define EE 64

typedef unsigned short u16;
typedef unsigned long long u64;
typedef float vf4 __attribute__((ext_vector_type(4)));

__device__ __forceinline__ float lrelu(float x) { return x > 0.f ? x : 0.2f * x; }

// K0: v6[vi][f] = sum_e W_d[f,e] * a_d[e]   (vi = 2*d + {0:a1, 1:a2})
// Separate tiny dispatch — R12/R16/R19 all proved inlining this into the
// 256..4096-block k_feat regresses (strided loads / LDS-occupancy collapse).
__global__ void k_prep(const float* __restrict__ Wf, const float* __restrict__ af1, const float* __restrict__ af2,
                       const float* __restrict__ Wb, const float* __restrict__ ab1, const float* __restrict__ ab2,
                       const float* __restrict__ Wg, const float* __restrict__ ag1, const float* __restrict__ ag2,
                       float* __restrict__ v6)
{
    const float* Ws[3]  = {Wf, Wb, Wg};
    const float* a1s[3] = {af1, ab1, ag1};
    const float* a2s[3] = {af2, ab2, ag2};
    int vi = blockIdx.x, f = threadIdx.x, dd = vi >> 1;
    const float* a = (vi & 1) ? a2s[dd] : a1s[dd];
    const float* W = Ws[dd] + (size_t)f * EE;
    float s = 0.f;
    #pragma unroll 8
    for (int e = 0; e < EE; ++e) s += W[e] * a[e];
    v6[vi * FF + f] = s;
}

// K1: 16 nodes per block. u = t@W.T via LDS-staged weight; out rows 0..63
// written as FULL 64-B LINES. Also s1/p. Blocks 0..15 zero the CSC counters.
__global__ __launch_bounds__(256)
void k_feat(const float* __restrict__ t, const float* __restrict__ weight,
            const float* __restrict__ v6,
            float* __restrict__ u, float* __restrict__ s1, float* __restrict__ p,
            float* __restrict__ out, int* __restrict__ ccnt)
{
    __shared__ float ww[64 * 129];   // weight[e][q] at e*129+q  (129: bank-spread)
    __shared__ float tt[16 * 130];   // t[node][q] at node*130+q
    __shared__ float vv[6 * FF];
    __shared__ float uacc[64 * 17];  // u[e][node] staging for transposed out write
    int b = blockIdx.x, tid = threadIdx.x;
    int n0 = b * 16;
    if (b < 16) ccnt[b * 256 + tid] = 0;
    const float4* w4 = reinterpret_cast<const float4*>(weight);
    for (int i = tid; i < 2048; i += 256) {
        float4 v = w4[i];
        int fi = i * 4, e = fi >> 7, q = fi & 127;
        float* dst = &ww[e * 129 + q];
        dst[0] = v.x; dst[1] = v.y; dst[2] = v.z; dst[3] = v.w;
    }
    const float4* t4 = reinterpret_cast<const float4*>(t + (size_t)n0 * FF);
    for (int i = tid; i < 512; i += 256) {
        float4 v = t4[i];
        int fi = i * 4, nd = fi >> 7, q = fi & 127;
        float* dst = &tt[nd * 130 + q];
        dst[0] = v.x; dst[1] = v.y; dst[2] = v.z; dst[3] = v.w;
    }
    for (int i = tid; i < 6 * FF; i += 256) vv[i] = v6[i];
    __syncthreads();
    int g = tid >> 6, lane = tid & 63;
    for (int k = 0; k < 4; ++k) {
        int nd = g * 4 + k;
        const float* trow = &tt[nd * 130];
        const float* wrow = &ww[lane * 129];
        float acc = 0.f;
        #pragma unroll 16
        for (int q = 0; q < 128; ++q) acc += wrow[q] * trow[q];
        u[(size_t)(n0 + nd) * EE + lane] = acc;
        uacc[lane * 17 + nd] = acc;
        float t0 = trow[lane], t1 = trow[64 + lane];
        for (int vi = 0; vi < 6; ++vi) {
            float x = t0 * vv[vi * FF + lane] + t1 * vv[vi * FF + 64 + lane];
            for (int off = 32; off; off >>= 1) x += __shfl_xor(x, off);
            if (lane == 0) {
                int dd = vi >> 1;
                if (vi & 1) p[dd * NN + n0 + nd] = x; else s1[dd * NN + n0 + nd] = x;
            }
        }
    }
    __syncthreads();
    int e = tid >> 2, io = (tid & 3) * 4;
    float* orow = out + (size_t)e * NN + n0 + io;
    orow[0] = uacc[e * 17 + io];
    orow[1] = uacc[e * 17 + io + 1];
    orow[2] = uacc[e * 17 + io + 2];
    orow[3] = uacc[e * 17 + io + 3];
}

// K2: streaming scan with NON-TEMPORAL adjacency loads (R16/R18-proven:
// 77 -> 42 us; no-allocate streaming avoids L2/L3 allocation overhead on a
// once-read 192 MB stream). ONE WAVE = ONE ROW.
__global__ __launch_bounds__(256, 8)
void k_scan(const float* __restrict__ Af, const float* __restrict__ Ab, const float* __restrict__ Ag,
            const float* __restrict__ p,
            u16* __restrict__ csr, int* __restrict__ cnt, float* __restrict__ s2,
            u16* __restrict__ csc, int* __restrict__ ccnt, int stride)
{
    int wid = threadIdx.x >> 6, lane = threadIdx.x & 63;
    int gr = blockIdx.x * 4 + wid;             // 0 .. 3*NN-1
    int d = gr >> 12, r = gr & (NN - 1);
    const float* A = d == 0 ? Af : (d == 1 ? Ab : Ag);
    const vf4* row4 = reinterpret_cast<const vf4*>(A + (size_t)r * NN);
    const float* pd = p + d * NN;

    u64 mask = 0ull;
    #pragma unroll
    for (int j = 0; j < 16; ++j) {
        vf4 L = __builtin_nontemporal_load(row4 + j * 64 + lane);
        unsigned mm = (L.x != 0.f ? 1u : 0u) | (L.y != 0.f ? 2u : 0u) |
                      (L.z != 0.f ? 4u : 0u) | (L.w != 0.f ? 8u : 0u);
        mask |= ((u64)mm) << (j * 4);
    }

    int lc = __popcll(mask);
    int sc = lc;
    for (int off = 1; off < 64; off <<= 1) {
        int o = __shfl_up(sc, off);
        if (lane >= off) sc += o;
    }
    int total = __shfl(sc, 63);
    int pos = sc - lc;
    u16* crow = csr + (size_t)gr * stride;
    float q = 0.f;
    u64 m = mask;
    while (m) {
        int b = __ffsll(m) - 1;
        m &= m - 1;
        int col = ((b >> 2) << 8) + (lane << 2) + (b & 3);
        if (pos < stride) crow[pos] = (u16)col;
        pos++;
        q += pd[col];
        if (d == 1) {
            int cp = atomicAdd(&ccnt[col], 1);
            if (cp < stride) csc[(size_t)col * stride + cp] = (u16)r;
        }
    }
    for (int off = 32; off; off >>= 1) q += __shfl_xor(q, off);
    if (lane == 0) {
        cnt[gr] = total;
        s2[gr] = q / fmaxf((float)total, 1.f);
    }
}

// K3: backward row denominators Zb[j] = sum_{col} exp(lrelu(s1b[j]+s2b[col]))
__global__ void k_zb(const float* __restrict__ s1, const float* __restrict__ s2,
                     const u16* __restrict__ csr, const int* __restrict__ cnt, int stride,
                     float* __restrict__ Zb)
{
    int tid = threadIdx.x, wave = tid >> 6, lane = tid & 63;
    int j = blockIdx.x * 4 + wave;
    int gr = NN + j;
    int nnz = min(cnt[gr], stride);
    const u16* crow = csr + (size_t)gr * stride;
    float s1j = s1[gr];
    const float* s2b = s2 + NN;
    float z = 0.f;
    if (lane < nnz)      z += __expf(lrelu(s1j + s2b[crow[lane]]));
    if (lane + 64 < nnz) z += __expf(lrelu(s1j + s2b[crow[lane + 64]]));
    for (int off = 32; off; off >>= 1) z += __shfl_xor(z, off);
    if (lane == 0) Zb[j] = z;
}

// K4: unified consumer, 16 rows per block (one wave = one row, 4 rows/wave,
// register+shfl gather), results staged in LDS and written as FULL 64-B LINES.
//  d==0: fwd (CSR) -> rows 64..127 ; d==1: bwd (CSC) -> 128..191 ; d==2: geo -> 192..255
__global__ __launch_bounds__(256)
void k_out(const float* __restrict__ u,
           const float* __restrict__ s1, const float* __restrict__ s2,
           const float* __restrict__ Zb,
           const u16* __restrict__ csr, const int* __restrict__ cnt,
           const u16* __restrict__ csc, const int* __restrict__ ccnt, int stride,
           float* __restrict__ out)
{
    __shared__ float oacc[16 * 66];
    int gr0 = blockIdx.x * 16;
    int d = gr0 >> 12, i0 = gr0 & (NN - 1);
    int wid = threadIdx.x >> 6, lane = threadIdx.x & 63;
    for (int k = 0; k < 4; ++k) {
        int lr = k * 4 + wid;
        int i = i0 + lr;
        int gr = gr0 + lr;
        int nnz;
        int c0v = 0, c1v = 0;
        float w0v = 0.f, w1v = 0.f;
        if (d == 1) {
            nnz = min(ccnt[i], stride);
            const u16* cc = csc + (size_t)i * stride;
            float s2i = s2[NN + i];
            if (lane < nnz)      { int j = cc[lane];      c0v = j; w0v = __expf(lrelu(s1[NN + j] + s2i)) / Zb[j]; }
            if (lane + 64 < nnz) { int j = cc[lane + 64]; c1v = j; w1v = __expf(lrelu(s1[NN + j] + s2i)) / Zb[j]; }
        } else {
            nnz = min(cnt[gr], stride);
            const u16* crow = csr + (size_t)gr * stride;
            float s1i = s1[gr];
            const float* s2d = s2 + d * NN;
            float z = 0.f;
            if (lane < nnz)      { int c = crow[lane];      c0v = c; w0v = __expf(lrelu(s1i + s2d[c])); z += w0v; }
            if (lane + 64 < nnz) { int c = crow[lane + 64]; c1v = c; w1v = __expf(lrelu(s1i + s2d[c])); z += w1v; }
            for (int off = 32; off; off >>= 1) z += __shfl_xor(z, off);
            float invz = z > 0.f ? 1.f / z : 0.f;
            w0v *= invz; w1v *= invz;
        }
        float a0 = 0.f, a1 = 0.f;
        int n0 = nnz < 64 ? nnz : 64;
        int kk = 0;
        for (; kk + 1 < n0; kk += 2) {
            int ca = __shfl(c0v, kk), cb = __shfl(c0v, kk + 1);
            float wa = __shfl(w0v, kk), wb = __shfl(w0v, kk + 1);
            a0 += wa * u[(size_t)ca * EE + lane];
            a1 += wb * u[(size_t)cb * EE + lane];
        }
        if (kk < n0)
            a0 += __shfl(w0v, kk) * u[(size_t)__shfl(c0v, kk) * EE + lane];
        int n1 = nnz - 64;
        kk = 0;
        for (; kk + 1 < n1; kk += 2) {
            int ca = __shfl(c1v, kk), cb = __shfl(c1v, kk + 1);
            float wa = __shfl(w1v, kk), wb = __shfl(w1v, kk + 1);
            a0 += wa * u[(size_t)ca * EE + lane];
            a1 += wb * u[(size_t)cb * EE + lane];
        }
        if (kk < n1)
            a0 += __shfl(w1v, kk) * u[(size_t)__shfl(c1v, kk) * EE + lane];
        oacc[lr * 66 + lane] = a0 + a1;
    }
    __syncthreads();
    int e = threadIdx.x >> 2, io = (threadIdx.x & 3) * 4;
    int base = 64 + (d << 6);
    float* orow = out + (size_t)(base + e) * NN + i0 + io;
    orow[0] = oacc[(io    ) * 66 + e];
    orow[1] = oacc[(io + 1) * 66 + e];
    orow[2] = oacc[(io + 2) * 66 + e];
    orow[3] = oacc[(io + 3) * 66 + e];
}

extern "C" void kernel_launch(void* const* d_in, const int* in_sizes, int n_in,
                              void* d_out, int out_size, void* d_ws, size_t ws_size,
                              hipStream_t stream)
{
    const float* t   = (const float*)d_in[0];
    const float* Ag  = (const float*)d_in[1];
    const float* Af  = (const float*)d_in[2];
    const float* Ab  = (const float*)d_in[3];
    const float* W   = (const float*)d_in[4];
    const float* Wf  = (const float*)d_in[5];
    const float* af1 = (const float*)d_in[6];
    const float* af2 = (const float*)d_in[7];
    const float* Wb  = (const float*)d_in[8];
    const float* ab1 = (const float*)d_in[9];
    const float* ab2 = (const float*)d_in[10];
    const float* Wg  = (const float*)d_in[11];
    const float* ag1 = (const float*)d_in[12];
    const float* ag2 = (const float*)d_in[13];
    float* out = (float*)d_out;

    float* ws = (float*)d_ws;
    float* v6  = ws;                              // 768
    float* s1  = v6 + 6 * FF;                     // 3N
    float* p   = s1 + 3 * NN;                     // 3N
    float* s2  = p + 3 * NN;                      // 3N
    float* Zb  = s2 + 3 * NN;                     // N
    float* u   = Zb + NN;                         // N*E
    int*   cnt  = (int*)(u + (size_t)NN * EE);    // 3N
    int*   ccnt = cnt + 3 * NN;                   // N
    u16*   csr  = (u16*)(ccnt + NN);              // 3N*stride
    // csc follows csr: N*stride

    size_t base_bytes = ((char*)csr) - ((char*)d_ws);
    int stride = 128;
    if (base_bytes + (size_t)4 * NN * 128 * 2 > ws_size) stride = 96;
    if (base_bytes + (size_t)4 * NN * 96 * 2 > ws_size)  stride = 64;
    u16* csc = csr + (size_t)3 * NN * stride;

    k_prep<<<6, 128, 0, stream>>>(Wf, af1, af2, Wb, ab1, ab2, Wg, ag1, ag2, v6);
    k_feat<<<NN / 16, 256, 0, stream>>>(t, W, v6, u, s1, p, out, ccnt);
    k_scan<<<3 * NN / 4, 256, 0, stream>>>(Af, Ab, Ag, p, csr, cnt, s2, csc, ccnt, stride);
    k_zb<<<NN / 4, 256, 0, stream>>>(s1, s2, csr, cnt, stride, Zb);
    k_out<<<3 * NN / 16, 256, 0, stream>>>(u, s1, s2, Zb, csr, cnt, csc, ccnt, stride, out);
}